// Round 9
// baseline (168.156 us; speedup 1.0000x reference)
//
#include <hip/hip_runtime.h>
#include <hip/hip_bf16.h>
#include <cstdint>

#define BATCH 8192
#define IN_F  4096
#define OUT_F 128
#define KSPLIT 4
#define KSL    (IN_F / KSPLIT)   // 1024 k per block
#define CH     256               // k per chunk
#define NCHUNK (KSL / CH)        // 4
#define OUT_N  ((size_t)BATCH * OUT_F)   // 1,048,576 floats = 4 MiB
// float32-rounded decay constants (tau_fac=100, tau_dep=200)
#define FD 0.99004983374916811f
#define DD 0.99501247919268232f

typedef __attribute__((ext_vector_type(4))) float f32x4;
typedef __attribute__((ext_vector_type(8))) float f32x8;
typedef __attribute__((ext_vector_type(8))) short bf16x8;

__device__ __forceinline__ unsigned short f2bf(float f){
  union { float f; unsigned u; } v; v.f = f;
  unsigned u = v.u;
  return (unsigned short)((u + 0x7FFFu + ((u >> 16) & 1u)) >> 16);  // RNE
}

// Pre-shuffle weight[128][4096] f32 -> fragment-major bf16 (proven R1-R8).
// Frag id f = (ks*8 + ct)*64 + l ; lane l holds weight[ct*16+(l&15)][ks*32+(l>>4)*8 + j]
__global__ __launch_bounds__(256) void prep_weight_kernel(const float* __restrict__ w,
                                                          unsigned short* __restrict__ wf){
  const int f  = blockIdx.x * 256 + threadIdx.x;   // 0..65535
  const int l  = f & 63;
  const int ct = (f >> 6) & 7;
  const int ks = f >> 9;                           // 0..127
  const int row = ct * 16 + (l & 15);
  const int k   = ks * 32 + ((l >> 4) << 3);
  const f32x4* src = reinterpret_cast<const f32x4*>(w + (size_t)row * IN_F + k);
  f32x4 a = src[0], b = src[1];
  union { bf16x8 v; unsigned short s[8]; } o;
  o.s[0]=f2bf(a[0]); o.s[1]=f2bf(a[1]); o.s[2]=f2bf(a[2]); o.s[3]=f2bf(a[3]);
  o.s[4]=f2bf(b[0]); o.s[5]=f2bf(b[1]); o.s[6]=f2bf(b[2]); o.s[7]=f2bf(b[3]);
  *reinterpret_cast<bf16x8*>(wf + (size_t)f * 8) = o.v;
}

// elementwise helper: one f32x8 triple -> un/xn stores + packed bf16 r (16B)
__device__ __forceinline__ uint4 stp_ew(const f32x8 s8, const f32x8 u8, const f32x8 x8,
                                        float* __restrict__ un_p, float* __restrict__ xn_p){
  f32x8 un, xn;
  unsigned short rb[8];
  #pragma unroll
  for (int j = 0; j < 8; ++j){
    const float s = s8[j], u = u8[j], x = x8[j];
    rb[j] = f2bf(u * x * s);
    const float ufd = u * FD;
    const float unj = ufd + 0.5f * (1.0f - ufd) * s;
    un[j] = unj;
    xn[j] = x * DD + (1.0f - x) * DD * (1.0f - s * unj);
  }
  *reinterpret_cast<f32x8*>(un_p) = un;
  *reinterpret_cast<f32x8*>(xn_p) = xn;
  uint4 pk;
  pk.x = (unsigned)rb[0] | ((unsigned)rb[1] << 16);
  pk.y = (unsigned)rb[2] | ((unsigned)rb[3] << 16);
  pk.z = (unsigned)rb[4] | ((unsigned)rb[5] << 16);
  pk.w = (unsigned)rb[6] | ((unsigned)rb[7] << 16);
  return pk;
}

// R7 structure (best measured), atomics removed. Block: 256 thr = 4 waves,
// 16 rows x 1024-K slice, 4 chunks of 256 k. Flat loads: 2 rows x 1KB runs
// per instruction. r (bf16) -> XOR-swizzled LDS; MFMA A-frags from LDS,
// B-frags from L2-resident wf. Epilogue: plain stores of the 16x128 partial
// into part[ksl] (d_ws); a tiny reduce kernel sums the 4 K-split partials.
__global__ __launch_bounds__(256, 4) void stp_fused6(
    const float* __restrict__ pre, const float* __restrict__ uin,
    const float* __restrict__ xin, const unsigned short* __restrict__ wf,
    float* __restrict__ part, float* __restrict__ un_out, float* __restrict__ xn_out)
{
  __shared__ unsigned char rbuf[2][16 * CH * 2];   // 2 x 8 KB

  const int tid = threadIdx.x;
  const int wv  = tid >> 6;
  const int l   = tid & 63;
  const int ksl     = blockIdx.x & (KSPLIT - 1);
  const int rowBase = (blockIdx.x >> 2) * 16;
  const int k0      = ksl * KSL;

  // flat-load geometry (2 rows per instruction, 1KB run per row)
  const int rl0 = 4 * wv + (l >> 5);               // local row for instr h=0
  const size_t g0 = (size_t)(rowBase + rl0) * IN_F + k0 + (size_t)(l & 31) * 8;
  const size_t rowStride2 = (size_t)2 * IN_F;      // h=1 rows are rl0+2

  // LDS write byte offsets (full logical addr, then XOR swizzle bits 4-6)
  const int wb0 = ((rl0    ) * 512 + (l & 31) * 16) ^ (((rl0    ) & 7) << 4);
  const int wb1 = ((rl0 + 2) * 512 + (l & 31) * 16) ^ (((rl0 + 2) & 7) << 4);

  // A-fragment read geometry: lane l -> row l&15, k-chunk (l>>4)*8
  const int ar  = l & 15;
  const int akc = (l >> 4) * 16;                   // byte offset within 64B k-step

  f32x4 acc0 = {0.f,0.f,0.f,0.f}, acc1 = {0.f,0.f,0.f,0.f};

  // prologue: issue chunk 0 loads
  f32x8 sA0 = *reinterpret_cast<const f32x8*>(pre + g0);
  f32x8 sA1 = *reinterpret_cast<const f32x8*>(pre + g0 + rowStride2);
  f32x8 uA0 = *reinterpret_cast<const f32x8*>(uin + g0);
  f32x8 uA1 = *reinterpret_cast<const f32x8*>(uin + g0 + rowStride2);
  f32x8 xA0 = *reinterpret_cast<const f32x8*>(xin + g0);
  f32x8 xA1 = *reinterpret_cast<const f32x8*>(xin + g0 + rowStride2);

  for (int c = 0; c < NCHUNK; ++c){
    const size_t gc = g0 + (size_t)c * CH;

    // issue next chunk's loads first — a full iteration of slack
    f32x8 sB0, sB1, uB0, uB1, xB0, xB1;
    if (c + 1 < NCHUNK){
      const size_t gn = g0 + (size_t)(c + 1) * CH;
      sB0 = *reinterpret_cast<const f32x8*>(pre + gn);
      sB1 = *reinterpret_cast<const f32x8*>(pre + gn + rowStride2);
      uB0 = *reinterpret_cast<const f32x8*>(uin + gn);
      uB1 = *reinterpret_cast<const f32x8*>(uin + gn + rowStride2);
      xB0 = *reinterpret_cast<const f32x8*>(xin + gn);
      xB1 = *reinterpret_cast<const f32x8*>(xin + gn + rowStride2);
    }

    // elementwise + un/xn stores (1KB runs) + r -> swizzled LDS
    uint4 p0 = stp_ew(sA0, uA0, xA0, un_out + gc, xn_out + gc);
    uint4 p1 = stp_ew(sA1, uA1, xA1, un_out + gc + rowStride2, xn_out + gc + rowStride2);
    *reinterpret_cast<uint4*>(&rbuf[c & 1][wb0]) = p0;
    *reinterpret_cast<uint4*>(&rbuf[c & 1][wb1]) = p1;

    __syncthreads();

    // MFMA phase: 8 k-steps of 32; wave wv owns col-tiles 2wv, 2wv+1
    const unsigned char* buf = rbuf[c & 1];
    const bf16x8* wfp = reinterpret_cast<const bf16x8*>(wf);
    #pragma unroll
    for (int ks = 0; ks < 8; ++ks){
      const int rb = (ar * 512 + ks * 64 + akc) ^ ((ar & 7) << 4);
      bf16x8 af = *reinterpret_cast<const bf16x8*>(buf + rb);
      const int gks = (k0 >> 5) + c * 8 + ks;      // global k-step 0..127
      bf16x8 b0 = wfp[(size_t)((gks * 8 + 2 * wv    ) << 6) + l];
      bf16x8 b1 = wfp[(size_t)((gks * 8 + 2 * wv + 1) << 6) + l];
      acc0 = __builtin_amdgcn_mfma_f32_16x16x32_bf16(af, b0, acc0, 0, 0, 0);
      acc1 = __builtin_amdgcn_mfma_f32_16x16x32_bf16(af, b1, acc1, 0, 0, 0);
    }

    if (c + 1 < NCHUNK){
      sA0 = sB0; sA1 = sB1; uA0 = uB0; uA1 = uB1; xA0 = xB0; xA1 = xB1;
    }
  }

  // epilogue: C/D layout col=lane&15, row=(lane>>4)*4+reg.
  // Plain stores of this block's 16x128 partial into part[ksl] (no atomics).
  float* pp = part + (size_t)ksl * OUT_N;
  const int colBase = wv * 32 + (l & 15);
  const int r0      = rowBase + ((l >> 4) << 2);
  #pragma unroll
  for (int rg = 0; rg < 4; ++rg){
    pp[(size_t)(r0 + rg) * OUT_F + colBase]      = acc0[rg];
    pp[(size_t)(r0 + rg) * OUT_F + colBase + 16] = acc1[rg];
  }
}

// Sum the 4 K-split partials (16 MB, L2/L3-hot) into out (4 MB).
__global__ __launch_bounds__(256) void reduce4_kernel(const float* __restrict__ part,
                                                      float* __restrict__ out){
  const size_t e = ((size_t)blockIdx.x * 256 + threadIdx.x) * 4;
  f32x4 s = *reinterpret_cast<const f32x4*>(part + e);
  s += *reinterpret_cast<const f32x4*>(part + OUT_N + e);
  s += *reinterpret_cast<const f32x4*>(part + 2 * OUT_N + e);
  s += *reinterpret_cast<const f32x4*>(part + 3 * OUT_N + e);
  *reinterpret_cast<f32x4*>(out + e) = s;
}

extern "C" void kernel_launch(void* const* d_in, const int* in_sizes, int n_in,
                              void* d_out, int out_size, void* d_ws, size_t ws_size,
                              hipStream_t stream){
  const float* pre = (const float*)d_in[0];
  const float* w   = (const float*)d_in[1];
  const float* u   = (const float*)d_in[2];
  const float* x   = (const float*)d_in[3];
  float* out    = (float*)d_out;
  float* un_out = out + OUT_N;
  float* xn_out = un_out + (size_t)BATCH * IN_F;

  // d_ws layout (ws_size >= 68 MB established by R5 forensics):
  //   [0, 1 MiB)        wf   — fragment-major bf16 weight
  //   [1 MiB, 17 MiB)   part — 4 x [8192][128] f32 K-split partials
  unsigned short* wf = (unsigned short*)d_ws;
  float* part = (float*)((char*)d_ws + (size_t)(1 << 20));

  prep_weight_kernel<<<256, 256, 0, stream>>>(w, wf);
  stp_fused6<<<(BATCH / 16) * KSPLIT, 256, 0, stream>>>(pre, u, x, wf, part, un_out, xn_out);
  reduce4_kernel<<<OUT_N / 4 / 256, 256, 0, stream>>>(part, out);
}